// Round 1
// baseline (2396.027 us; speedup 1.0000x reference)
//
#include <hip/hip_runtime.h>

// Problem constants (from reference): B=32, C=1024, N=2048, K=64
#define BB_ 32
#define CC_ 1024
#define NN_ 2048
#define KK_ 64

typedef __bf16 bf16x8 __attribute__((ext_vector_type(8)));
typedef __bf16 bf16x2 __attribute__((ext_vector_type(2)));
typedef float f32x4 __attribute__((ext_vector_type(4)));

__device__ inline unsigned short f2bf_rn(float f) {
    unsigned u = __float_as_uint(f);
    unsigned r = (u + 0x7fffu + ((u >> 16) & 1u)) >> 16;
    return (unsigned short)r;
}

__device__ inline unsigned pack_bf16_rn(float f0, float f1) {
#if __has_builtin(__builtin_amdgcn_cvt_pk_bf16_f32)
    union { bf16x2 v; unsigned u; } x;
    x.v = __builtin_amdgcn_cvt_pk_bf16_f32(f0, f1);
    return x.u;
#else
    return (unsigned)f2bf_rn(f0) | ((unsigned)f2bf_rn(f1) << 16);
#endif
}

// ---------------------------------------------------------------------------
// norms: n[b][i] = sum_c X[b][c][i]^2   (8-way chunked accumulation for accuracy)
// grid (8, 32) x 256
// ---------------------------------------------------------------------------
__global__ void norm_kernel(const float* __restrict__ X, float* __restrict__ n) {
    int b = blockIdx.y;
    int i = blockIdx.x * 256 + threadIdx.x;
    const float* xb = X + (size_t)b * CC_ * NN_ + i;
    float a[8];
#pragma unroll
    for (int j = 0; j < 8; j++) a[j] = 0.f;
    for (int c = 0; c < CC_; c += 8) {
#pragma unroll
        for (int j = 0; j < 8; j++) {
            float v = xb[(size_t)(c + j) * NN_];
            a[j] += v * v;
        }
    }
    float s = ((a[0] + a[1]) + (a[2] + a[3])) + ((a[4] + a[5]) + (a[6] + a[7]));
    n[b * NN_ + i] = s;
}

// ---------------------------------------------------------------------------
// gram: G[lb][i][j] = sum_c X[b][c][i] * X[b][c][j], split-bf16 3-term MFMA.
// 128x128 tile per block, BK=32, 4 waves in 2x2, each wave 4x4 of 16x16x32.
// LDS tiles stored [col][k], row stride 40 bf16 (80B: 16B-aligned, 2-way banks).
// grid (256, gs) x 256
// ---------------------------------------------------------------------------
__global__ __launch_bounds__(256, 2) void gram_kernel(const float* __restrict__ X,
                                                      float* __restrict__ G, int g0) {
    int lb = blockIdx.y;
    int b = g0 + lb;
    int tm = blockIdx.x & 15, tn = blockIdx.x >> 4;
    int t = threadIdx.x;
    __shared__ __align__(16) unsigned sAh[128 * 20];
    __shared__ __align__(16) unsigned sAl[128 * 20];
    __shared__ __align__(16) unsigned sBh[128 * 20];
    __shared__ __align__(16) unsigned sBl[128 * 20];

    const float* Xb = X + (size_t)b * CC_ * NN_;
    int i0 = tm * 128, j0 = tn * 128;
    int w = t >> 6, l = t & 63;
    int m0w = (w & 1) * 64, n0w = (w >> 1) * 64;

    f32x4 zero = {0.f, 0.f, 0.f, 0.f};
    f32x4 acc[4][4];
#pragma unroll
    for (int mt = 0; mt < 4; mt++)
#pragma unroll
        for (int nt = 0; nt < 4; nt++) acc[mt][nt] = zero;

    int cm = t & 127;          // column within 128-wide panel (coalesced across lanes)
    int kb = (t >> 7) * 2;     // 0 or 2
    int q = l >> 4, rr = l & 15;

    for (int kt = 0; kt < 32; kt++) {
        int k0 = kt * 32;
        __syncthreads();
#pragma unroll
        for (int j = 0; j < 8; j++) {
            int k = kb + 4 * j;  // pairs (k,k+1); two thread-halves cover all 32 k
            // A panel (columns i0..i0+127)
            float f0 = Xb[(size_t)(k0 + k) * NN_ + i0 + cm];
            float f1 = Xb[(size_t)(k0 + k + 1) * NN_ + i0 + cm];
            unsigned hp = pack_bf16_rn(f0, f1);
            float h0f = __uint_as_float((hp & 0xffffu) << 16);
            float h1f = __uint_as_float(hp & 0xffff0000u);
            unsigned lp = pack_bf16_rn(f0 - h0f, f1 - h1f);
            sAh[cm * 20 + (k >> 1)] = hp;
            sAl[cm * 20 + (k >> 1)] = lp;
            // B panel (columns j0..j0+127)
            f0 = Xb[(size_t)(k0 + k) * NN_ + j0 + cm];
            f1 = Xb[(size_t)(k0 + k + 1) * NN_ + j0 + cm];
            hp = pack_bf16_rn(f0, f1);
            h0f = __uint_as_float((hp & 0xffffu) << 16);
            h1f = __uint_as_float(hp & 0xffff0000u);
            lp = pack_bf16_rn(f0 - h0f, f1 - h1f);
            sBh[cm * 20 + (k >> 1)] = hp;
            sBl[cm * 20 + (k >> 1)] = lp;
        }
        __syncthreads();

        bf16x8 ah[4], al[4], bh[4], bl[4];
#pragma unroll
        for (int mt = 0; mt < 4; mt++) {
            int row = m0w + mt * 16 + rr;
            union { uint4 u; bf16x8 v; } ua, ub;
            ua.u = *(const uint4*)&sAh[row * 20 + q * 4];
            ub.u = *(const uint4*)&sAl[row * 20 + q * 4];
            ah[mt] = ua.v; al[mt] = ub.v;
            int rown = n0w + mt * 16 + rr;
            union { uint4 u; bf16x8 v; } uc, ud;
            uc.u = *(const uint4*)&sBh[rown * 20 + q * 4];
            ud.u = *(const uint4*)&sBl[rown * 20 + q * 4];
            bh[mt] = uc.v; bl[mt] = ud.v;
        }
#pragma unroll
        for (int mt = 0; mt < 4; mt++)
#pragma unroll
            for (int nt = 0; nt < 4; nt++) {
                acc[mt][nt] = __builtin_amdgcn_mfma_f32_16x16x32_bf16(ah[mt], bh[nt], acc[mt][nt], 0, 0, 0);
                acc[mt][nt] = __builtin_amdgcn_mfma_f32_16x16x32_bf16(ah[mt], bl[nt], acc[mt][nt], 0, 0, 0);
                acc[mt][nt] = __builtin_amdgcn_mfma_f32_16x16x32_bf16(al[mt], bh[nt], acc[mt][nt], 0, 0, 0);
            }
    }

    // epilogue: C/D layout col=lane&15, row=(lane>>4)*4+reg
    float* Gb = G + (size_t)lb * NN_ * NN_;
    int cc = l & 15;
#pragma unroll
    for (int mt = 0; mt < 4; mt++)
#pragma unroll
        for (int nt = 0; nt < 4; nt++)
#pragma unroll
            for (int r = 0; r < 4; r++) {
                int gi = i0 + m0w + mt * 16 + q * 4 + r;
                int gj = j0 + n0w + nt * 16 + cc;
                Gb[(size_t)gi * NN_ + gj] = acc[mt][nt][r];
            }
}

// ---------------------------------------------------------------------------
// fps: one block per batch; dists in registers (8 pts/thread); 63 iterations of
// read-G-row + min-update + first-max argmax (tie -> lower index, numpy semantics).
// grid (gs) x 256
// ---------------------------------------------------------------------------
__global__ void fps_kernel(const float* __restrict__ G, const float* __restrict__ n,
                           int* __restrict__ idx, int g0) {
    int lb = blockIdx.x;
    int b = g0 + lb;
    int t = threadIdx.x;
    const float* Gb = G + (size_t)lb * NN_ * NN_;
    const float* nb = n + b * NN_;
    __shared__ float swv[4];
    __shared__ int swi[4];
    __shared__ int sfar;

    float dist[8], nr[8];
#pragma unroll
    for (int r = 0; r < 8; r++) {
        nr[r] = nb[t + 256 * r];
        dist[r] = 1e10f;
    }
    if (t == 0) idx[b * KK_] = 0;
    int far = 0;
    for (int k = 1; k < KK_; k++) {
        float nf = nb[far];
        const float* grow = Gb + (size_t)far * NN_;
#pragma unroll
        for (int r = 0; r < 8; r++) {
            float d = nr[r] + nf - 2.f * grow[t + 256 * r];
            dist[r] = fminf(dist[r], d);
        }
        float v = dist[0];
        int pi = t;
#pragma unroll
        for (int r = 1; r < 8; r++)
            if (dist[r] > v) { v = dist[r]; pi = t + 256 * r; }
#pragma unroll
        for (int off = 32; off > 0; off >>= 1) {
            float ov = __shfl_down(v, off);
            int oi = __shfl_down(pi, off);
            if (ov > v || (ov == v && oi < pi)) { v = ov; pi = oi; }
        }
        int w = t >> 6;
        if ((t & 63) == 0) { swv[w] = v; swi[w] = pi; }
        __syncthreads();
        if (t == 0) {
            float bv = swv[0]; int bi = swi[0];
            for (int ww = 1; ww < 4; ww++)
                if (swv[ww] > bv || (swv[ww] == bv && swi[ww] < bi)) { bv = swv[ww]; bi = swi[ww]; }
            sfar = bi;
            idx[b * KK_ + k] = bi;
        }
        __syncthreads();
        far = sfar;
    }
}

// ---------------------------------------------------------------------------
// x1: cat[b][o][k] = sum_i gf[b][i]*ps1_w[i][o][k] + ps1_b[o]  for o in [0,128)
// thread = one (o,k), 8 batches per block. gf reads are block-uniform (scalar).
// grid (128) x 256
// ---------------------------------------------------------------------------
__global__ void x1_kernel(const float* __restrict__ gf, const float* __restrict__ w,
                          const float* __restrict__ bias, float* __restrict__ cat) {
    int bid = blockIdx.x;
    int t = threadIdx.x;
    int okg = bid & 31, bg = bid >> 5;
    int ok = okg * 256 + t;
    int o = ok >> 6, k = ok & 63;
    float acc[8];
#pragma unroll
    for (int j = 0; j < 8; j++) acc[j] = 0.f;
    const float* g = gf + (size_t)(bg * 8) * CC_;
    for (int i = 0; i < CC_; i++) {
        float wv = w[(size_t)(i * 128 + o) * KK_ + k];
#pragma unroll
        for (int j = 0; j < 8; j++) acc[j] += g[j * CC_ + i] * wv;
    }
    float bv = bias[o];
#pragma unroll
    for (int j = 0; j < 8; j++)
        cat[((size_t)(bg * 8 + j) * 2176 + o) * KK_ + k] = acc[j] + bv;
}

// ---------------------------------------------------------------------------
// catfill: channels [128,1152) = gathered point features; [1152,2176) = gf bcast
// grid (512, 32) x 256
// ---------------------------------------------------------------------------
__global__ void catfill_kernel(const float* __restrict__ X, const float* __restrict__ gf,
                               const int* __restrict__ idx, float* __restrict__ cat) {
    int b = blockIdx.y;
    int t = threadIdx.x;
    int ch = 128 + blockIdx.x * 4 + (t >> 6);
    int k = t & 63;
    float v;
    if (ch < 1152) {
        int c = ch - 128;
        int ik = idx[b * KK_ + k];
        v = X[((size_t)b * CC_ + c) * NN_ + ik];
    } else {
        v = gf[b * CC_ + (ch - 1152)];
    }
    cat[((size_t)b * 2176 + ch) * KK_ + k] = v;
}

// ---------------------------------------------------------------------------
// mlp1: t1 = relu(m1c1@cat + b1), sc = m1sc@cat + bsc.  thread = one (o,k).
// grid (32, 32) x 256
// ---------------------------------------------------------------------------
__global__ void mlp1_kernel(const float* __restrict__ cat, const float* __restrict__ w1,
                            const float* __restrict__ b1, const float* __restrict__ wsc,
                            const float* __restrict__ bsc, float* __restrict__ t1,
                            float* __restrict__ sc) {
    int b = blockIdx.y;
    int og = blockIdx.x;
    int t = threadIdx.x;
    int o = og * 4 + (t >> 6);
    int k = t & 63;
    const float* cb = cat + (size_t)b * 2176 * KK_;
    const float* wr1 = w1 + (size_t)o * 2176;
    const float* wrs = wsc + (size_t)o * 2176;
    float a1 = 0.f, a2 = 0.f;
    for (int i = 0; i < 2176; i++) {
        float cv = cb[i * KK_ + k];
        a1 += wr1[i] * cv;
        a2 += wrs[i] * cv;
    }
    size_t oidx = ((size_t)b * 128 + o) * KK_ + k;
    t1[oidx] = fmaxf(a1 + b1[o], 0.f);
    sc[oidx] = a2 + bsc[o];
}

// ---------------------------------------------------------------------------
// mlp2: h = m1c2@t1 + b2 + sc; r2 = relu(m2c1@h + b3); out = (m2c2@r2 + b4)^T
// one block per batch, all staged in LDS.
// grid (32) x 256
// ---------------------------------------------------------------------------
__global__ void mlp2_kernel(const float* __restrict__ t1, const float* __restrict__ sc,
                            const float* __restrict__ w2, const float* __restrict__ b2,
                            const float* __restrict__ w3, const float* __restrict__ b3,
                            const float* __restrict__ w4, const float* __restrict__ b4,
                            float* __restrict__ out) {
    __shared__ float sT[128 * 64];
    __shared__ float sH[128 * 64];
    __shared__ float sR[64 * 64];
    int b = blockIdx.x, t = threadIdx.x;
    const float* t1b = t1 + (size_t)b * 128 * 64;
    const float* scb = sc + (size_t)b * 128 * 64;
    for (int j = t; j < 128 * 64; j += 256) sT[j] = t1b[j];
    __syncthreads();
    int k = t & 63, og = t >> 6;
    for (int rep = 0; rep < 32; rep++) {
        int o = og * 32 + rep;
        float acc = b2[o] + scb[o * 64 + k];
        const float* wr = w2 + o * 128;
        for (int i = 0; i < 128; i++) acc += wr[i] * sT[i * 64 + k];
        sH[o * 64 + k] = acc;
    }
    __syncthreads();
    for (int rep = 0; rep < 16; rep++) {
        int o = og * 16 + rep;
        float acc = b3[o];
        const float* wr = w3 + o * 128;
        for (int i = 0; i < 128; i++) acc += wr[i] * sH[i * 64 + k];
        sR[o * 64 + k] = fmaxf(acc, 0.f);
    }
    __syncthreads();
    if (t < 192) {
        int o = t % 3;
        int kk = t / 3;
        float acc = b4[o];
        const float* wr = w4 + o * 64;
        for (int i = 0; i < 64; i++) acc += wr[i] * sR[i * 64 + kk];
        out[((size_t)b * KK_ + kk) * 3 + o] = acc;
    }
}

// ---------------------------------------------------------------------------
extern "C" void kernel_launch(void* const* d_in, const int* in_sizes, int n_in,
                              void* d_out, int out_size, void* d_ws, size_t ws_size,
                              hipStream_t stream) {
    const float* X    = (const float*)d_in[0];   // point_feat (B,C,N)
    const float* gf   = (const float*)d_in[1];   // global_feat (B,C)
    const float* ps1w = (const float*)d_in[2];   // (C,128,K)
    const float* ps1b = (const float*)d_in[3];
    const float* w1   = (const float*)d_in[4];   // m1c1 (128,2176)
    const float* b1   = (const float*)d_in[5];
    const float* w2   = (const float*)d_in[6];   // m1c2 (128,128)
    const float* b2   = (const float*)d_in[7];
    const float* wsc  = (const float*)d_in[8];   // m1sc (128,2176)
    const float* bscp = (const float*)d_in[9];
    const float* w3   = (const float*)d_in[10];  // m2c1 (64,128)
    const float* b3   = (const float*)d_in[11];
    const float* w4   = (const float*)d_in[12];  // m2c2 (3,64)
    const float* b4   = (const float*)d_in[13];
    float* out = (float*)d_out;

    char* ws = (char*)d_ws;
    const size_t G_PER = (size_t)NN_ * NN_ * 4;                      // 16 MB / batch
    const size_t N_B = (size_t)BB_ * NN_ * 4;                        // 256 KB
    const size_t IDX_B = (size_t)BB_ * KK_ * 4;                      // 8 KB
    const size_t CAT_B = (size_t)BB_ * 2176 * KK_ * 4;               // 17.8 MB
    const size_t T1_B = (size_t)BB_ * 128 * KK_ * 4;                 // 1 MB
    size_t restBytes = N_B + IDX_B + CAT_B + 2 * T1_B;
    int gs = 8;
    while (gs > 1 && (size_t)gs * G_PER + restBytes > ws_size) gs >>= 1;

    float* Gws = (float*)ws;
    char* p = ws + (size_t)gs * G_PER;
    float* nws = (float*)p;  p += N_B;
    int* idxws = (int*)p;    p += IDX_B;
    float* cat = (float*)p;  p += CAT_B;
    float* t1  = (float*)p;  p += T1_B;
    float* sc  = (float*)p;

    norm_kernel<<<dim3(8, BB_), 256, 0, stream>>>(X, nws);
    for (int g0 = 0; g0 < BB_; g0 += gs) {
        gram_kernel<<<dim3(256, gs), 256, 0, stream>>>(X, Gws, g0);
        fps_kernel<<<gs, 256, 0, stream>>>(Gws, nws, idxws, g0);
    }
    x1_kernel<<<128, 256, 0, stream>>>(gf, ps1w, ps1b, cat);
    catfill_kernel<<<dim3(512, BB_), 256, 0, stream>>>(X, gf, idxws, cat);
    mlp1_kernel<<<dim3(32, BB_), 256, 0, stream>>>(cat, w1, b1, wsc, bscp, t1, sc);
    mlp2_kernel<<<BB_, 256, 0, stream>>>(t1, sc, w2, b2, w3, b3, w4, b4, out);
}

// Round 2
// 1759.270 us; speedup vs baseline: 1.3619x; 1.3619x over previous
//
#include <hip/hip_runtime.h>

// Problem constants: B=32, C=1024, N=2048, K=64
#define BB_ 32
#define CC_ 1024
#define NN_ 2048
#define KK_ 64

typedef __bf16 bf16x8 __attribute__((ext_vector_type(8)));
typedef __bf16 bf16x2 __attribute__((ext_vector_type(2)));
typedef float f32x4 __attribute__((ext_vector_type(4)));
typedef unsigned int u32;

__device__ inline unsigned short f2bf_rn(float f) {
    unsigned u = __float_as_uint(f);
    unsigned r = (u + 0x7fffu + ((u >> 16) & 1u)) >> 16;
    return (unsigned short)r;
}

__device__ inline unsigned pack_bf16_rn(float f0, float f1) {
#if __has_builtin(__builtin_amdgcn_cvt_pk_bf16_f32)
    union { bf16x2 v; unsigned u; } x;
    x.v = __builtin_amdgcn_cvt_pk_bf16_f32(f0, f1);
    return x.u;
#else
    return (unsigned)f2bf_rn(f0) | ((unsigned)f2bf_rn(f1) << 16);
#endif
}

__device__ inline void gload16(const void* g, void* l) {
    __builtin_amdgcn_global_load_lds(
        (const __attribute__((address_space(1))) u32*)g,
        (__attribute__((address_space(3))) u32*)l, 16, 0, 0);
}

// ---------------------------------------------------------------------------
// convert: X (fp32, B,C,N) -> Xc split-bf16, per group.
// Layout: Xc[lb][kt][n] is 128 B: 8 chunks of 16 B (8 bf16).
// Chunk for term t (0=hi,1=lo), k-quad q sits at position p = (4t+q) ^ (n&7).
// grid (8, 32, gs) x 256
// ---------------------------------------------------------------------------
__global__ void convert_kernel(const float* __restrict__ X,
                               unsigned char* __restrict__ Xc, int g0) {
    int lb = blockIdx.z, kt = blockIdx.y;
    int n = blockIdx.x * 256 + threadIdx.x;
    int b = g0 + lb;
    const float* Xb = X + (size_t)b * CC_ * NN_;
    unsigned char* dst = Xc + (((size_t)lb * 32 + kt) * NN_ + n) * 128;
    int sw = n & 7;
#pragma unroll
    for (int q = 0; q < 4; q++) {
        float f[8];
#pragma unroll
        for (int j = 0; j < 8; j++)
            f[j] = Xb[(size_t)(kt * 32 + q * 8 + j) * NN_ + n];
        union { unsigned u[4]; uint4 v; } hq, lq;
#pragma unroll
        for (int j2 = 0; j2 < 4; j2++) {
            float a = f[2 * j2], c = f[2 * j2 + 1];
            unsigned hp = pack_bf16_rn(a, c);
            float h0f = __uint_as_float((hp & 0xffffu) << 16);
            float h1f = __uint_as_float(hp & 0xffff0000u);
            hq.u[j2] = hp;
            lq.u[j2] = pack_bf16_rn(a - h0f, c - h1f);
        }
        int p = q ^ sw;
        *(uint4*)(dst + (p << 4)) = hq.v;
        *(uint4*)(dst + ((p ^ 4) << 4)) = lq.v;
    }
}

// ---------------------------------------------------------------------------
// fps block body: one block handles one batch; 63 sequential min-update+argmax
// steps over G rows. Norms come from the diagonal of G. One barrier per step
// (double-buffered wave results). Tie -> lower index (numpy argmax semantics).
// ---------------------------------------------------------------------------
__device__ void fps_block(const float* Gb, int* idx, int b) {
    __shared__ float swv[2][4];
    __shared__ int swi[2][4];
    int t = threadIdx.x;
    float dist[8], nr[8];
#pragma unroll
    for (int r = 0; r < 8; r++) {
        nr[r] = Gb[(size_t)(t + 256 * r) * (NN_ + 1)];
        dist[r] = 1e10f;
    }
    if (t == 0) idx[b * KK_] = 0;
    int far = 0;
    for (int k = 1; k < KK_; k++) {
        float nf = Gb[(size_t)far * (NN_ + 1)];
        const float* grow = Gb + (size_t)far * NN_;
        float v = -1.f;
        int pi = 0;
#pragma unroll
        for (int r = 0; r < 8; r++) {
            float d = nr[r] + nf - 2.f * grow[t + 256 * r];
            dist[r] = fminf(dist[r], d);
            if (dist[r] > v) { v = dist[r]; pi = t + 256 * r; }
        }
#pragma unroll
        for (int off = 32; off; off >>= 1) {
            float ov = __shfl_down(v, off);
            int oi = __shfl_down(pi, off);
            if (ov > v || (ov == v && oi < pi)) { v = ov; pi = oi; }
        }
        int par = k & 1;
        if ((t & 63) == 0) { swv[par][t >> 6] = v; swi[par][t >> 6] = pi; }
        __syncthreads();
        float bv = swv[par][0];
        int bi = swi[par][0];
#pragma unroll
        for (int ww = 1; ww < 4; ww++) {
            float wv2 = swv[par][ww]; int wi2 = swi[par][ww];
            if (wv2 > bv || (wv2 == bv && wi2 < bi)) { bv = wv2; bi = wi2; }
        }
        far = bi;
        if (t == 0) idx[b * KK_ + k] = bi;
    }
}

// ---------------------------------------------------------------------------
// gram (+merged fps): blocks [0,nFps) run fps on Gprev (resident from t=0);
// the rest compute G = X^T X via split-bf16 3-term MFMA, staging through
// global_load_lds from the pre-converted swizzled Xc.
// gram grid part: gs*256 blocks (16x16 tiles of 128x128).
// ---------------------------------------------------------------------------
__global__ __launch_bounds__(256, 2) void gram_fps_kernel(
    const unsigned char* __restrict__ Xc, float* __restrict__ G,
    const float* Gprev, int* __restrict__ idx, int nFps, int g0prev) {
    if ((int)blockIdx.x < nFps) {
        fps_block(Gprev + (size_t)blockIdx.x * NN_ * NN_, idx, g0prev + blockIdx.x);
        return;
    }
    int bx = blockIdx.x - nFps;
    int lb = bx >> 8;
    int tile = bx & 255;
    int tm = tile & 15, tn = tile >> 4;
    int t = threadIdx.x;
    __shared__ __align__(16) unsigned char sA[16384];
    __shared__ __align__(16) unsigned char sB[16384];

    const unsigned char* XcB = Xc + (size_t)lb * 32 * NN_ * 128;
    int w = t >> 6, l = t & 63;
    int m0w = (w & 1) * 64, n0w = (w >> 1) * 64;
    int q = l >> 4, rr = l & 15;

    f32x4 zero = {0.f, 0.f, 0.f, 0.f};
    f32x4 acc[4][4];
#pragma unroll
    for (int mt = 0; mt < 4; mt++)
#pragma unroll
        for (int nt = 0; nt < 4; nt++) acc[mt][nt] = zero;

    for (int kt = 0; kt < 32; kt++) {
        const unsigned char* Ab = XcB + ((size_t)kt * NN_ + (size_t)tm * 128) * 128;
        const unsigned char* Bb = XcB + ((size_t)kt * NN_ + (size_t)tn * 128) * 128;
        __syncthreads();   // LDS free (prev iter reads done)
#pragma unroll
        for (int r = 0; r < 4; r++) {
            gload16(Ab + r * 4096 + t * 16, sA + r * 4096 + t * 16);
            gload16(Bb + r * 4096 + t * 16, sB + r * 4096 + t * 16);
        }
        __syncthreads();   // staging complete

        bf16x8 ah[4], al[4], bh[4], bl[4];
#pragma unroll
        for (int mt = 0; mt < 4; mt++) {
            int ra = m0w + mt * 16 + rr;
            int pa = q ^ (ra & 7);
            ah[mt] = *(const bf16x8*)(sA + ra * 128 + (pa << 4));
            al[mt] = *(const bf16x8*)(sA + ra * 128 + ((pa ^ 4) << 4));
            int rb = n0w + mt * 16 + rr;
            int pb = q ^ (rb & 7);
            bh[mt] = *(const bf16x8*)(sB + rb * 128 + (pb << 4));
            bl[mt] = *(const bf16x8*)(sB + rb * 128 + ((pb ^ 4) << 4));
        }
#pragma unroll
        for (int mt = 0; mt < 4; mt++)
#pragma unroll
            for (int nt = 0; nt < 4; nt++) {
                acc[mt][nt] = __builtin_amdgcn_mfma_f32_16x16x32_bf16(ah[mt], bh[nt], acc[mt][nt], 0, 0, 0);
                acc[mt][nt] = __builtin_amdgcn_mfma_f32_16x16x32_bf16(ah[mt], bl[nt], acc[mt][nt], 0, 0, 0);
                acc[mt][nt] = __builtin_amdgcn_mfma_f32_16x16x32_bf16(al[mt], bh[nt], acc[mt][nt], 0, 0, 0);
            }
    }

    // epilogue: C/D layout col=lane&15, row=(lane>>4)*4+reg
    float* Gb = G + (size_t)lb * NN_ * NN_;
    int i0 = tm * 128, j0 = tn * 128;
    int cc = l & 15;
#pragma unroll
    for (int mt = 0; mt < 4; mt++)
#pragma unroll
        for (int nt = 0; nt < 4; nt++)
#pragma unroll
            for (int r = 0; r < 4; r++) {
                int gi = i0 + m0w + mt * 16 + q * 4 + r;
                int gj = j0 + n0w + nt * 16 + cc;
                Gb[(size_t)gi * NN_ + gj] = acc[mt][nt][r];
            }
}

// ---------------------------------------------------------------------------
// x1 (+merged last fps): blocks [0,nFps) run fps; the rest compute
// cat[b][o][k] = sum_i gf[b][i]*ps1_w[i][o][k] + ps1_b[o] for o in [0,128).
// x1 part: 128 blocks (32 ok-groups x 4 batch-groups of 8).
// ---------------------------------------------------------------------------
__global__ void x1_fps_kernel(const float* __restrict__ gf, const float* __restrict__ w,
                              const float* __restrict__ bias, float* __restrict__ cat,
                              const float* Gprev, int* __restrict__ idx,
                              int g0prev, int nFps) {
    if ((int)blockIdx.x < nFps) {
        fps_block(Gprev + (size_t)blockIdx.x * NN_ * NN_, idx, g0prev + blockIdx.x);
        return;
    }
    int bid = blockIdx.x - nFps;
    int t = threadIdx.x;
    int okg = bid & 31, bg = bid >> 5;
    int ok = okg * 256 + t;
    int o = ok >> 6, k = ok & 63;
    float acc[8];
#pragma unroll
    for (int j = 0; j < 8; j++) acc[j] = 0.f;
    const float* g = gf + (size_t)(bg * 8) * CC_;
    for (int i = 0; i < CC_; i++) {
        float wv = w[(size_t)(i * 128 + o) * KK_ + k];
#pragma unroll
        for (int j = 0; j < 8; j++) acc[j] += g[j * CC_ + i] * wv;
    }
    float bv = bias[o];
#pragma unroll
    for (int j = 0; j < 8; j++)
        cat[((size_t)(bg * 8 + j) * 2176 + o) * KK_ + k] = acc[j] + bv;
}

// ---------------------------------------------------------------------------
// catfill: channels [128,1152) = gathered point features; [1152,2176) = gf
// grid (512, 32) x 256
// ---------------------------------------------------------------------------
__global__ void catfill_kernel(const float* __restrict__ X, const float* __restrict__ gf,
                               const int* __restrict__ idx, float* __restrict__ cat) {
    int b = blockIdx.y;
    int t = threadIdx.x;
    int ch = 128 + blockIdx.x * 4 + (t >> 6);
    int k = t & 63;
    float v;
    if (ch < 1152) {
        int c = ch - 128;
        int ik = idx[b * KK_ + k];
        v = X[((size_t)b * CC_ + c) * NN_ + ik];
    } else {
        v = gf[b * CC_ + (ch - 1152)];
    }
    cat[((size_t)b * 2176 + ch) * KK_ + k] = v;
}

// ---------------------------------------------------------------------------
// mlp1: t1 = relu(m1c1@cat + b1), sc = m1sc@cat + bsc.  grid (32,32) x 256
// ---------------------------------------------------------------------------
__global__ void mlp1_kernel(const float* __restrict__ cat, const float* __restrict__ w1,
                            const float* __restrict__ b1, const float* __restrict__ wsc,
                            const float* __restrict__ bsc, float* __restrict__ t1,
                            float* __restrict__ sc) {
    int b = blockIdx.y;
    int og = blockIdx.x;
    int t = threadIdx.x;
    int o = og * 4 + (t >> 6);
    int k = t & 63;
    const float* cb = cat + (size_t)b * 2176 * KK_;
    const float* wr1 = w1 + (size_t)o * 2176;
    const float* wrs = wsc + (size_t)o * 2176;
    float a1 = 0.f, a2 = 0.f;
    for (int i = 0; i < 2176; i++) {
        float cv = cb[i * KK_ + k];
        a1 += wr1[i] * cv;
        a2 += wrs[i] * cv;
    }
    size_t oidx = ((size_t)b * 128 + o) * KK_ + k;
    t1[oidx] = fmaxf(a1 + b1[o], 0.f);
    sc[oidx] = a2 + bsc[o];
}

// ---------------------------------------------------------------------------
// mlp2: h = m1c2@t1 + b2 + sc; r2 = relu(m2c1@h + b3); out = (m2c2@r2 + b4)^T
// grid (32) x 256
// ---------------------------------------------------------------------------
__global__ void mlp2_kernel(const float* __restrict__ t1, const float* __restrict__ sc,
                            const float* __restrict__ w2, const float* __restrict__ b2,
                            const float* __restrict__ w3, const float* __restrict__ b3,
                            const float* __restrict__ w4, const float* __restrict__ b4,
                            float* __restrict__ out) {
    __shared__ float sT[128 * 64];
    __shared__ float sH[128 * 64];
    __shared__ float sR[64 * 64];
    int b = blockIdx.x, t = threadIdx.x;
    const float* t1b = t1 + (size_t)b * 128 * 64;
    const float* scb = sc + (size_t)b * 128 * 64;
    for (int j = t; j < 128 * 64; j += 256) sT[j] = t1b[j];
    __syncthreads();
    int k = t & 63, og = t >> 6;
    for (int rep = 0; rep < 32; rep++) {
        int o = og * 32 + rep;
        float acc = b2[o] + scb[o * 64 + k];
        const float* wr = w2 + o * 128;
        for (int i = 0; i < 128; i++) acc += wr[i] * sT[i * 64 + k];
        sH[o * 64 + k] = acc;
    }
    __syncthreads();
    for (int rep = 0; rep < 16; rep++) {
        int o = og * 16 + rep;
        float acc = b3[o];
        const float* wr = w3 + o * 128;
        for (int i = 0; i < 128; i++) acc += wr[i] * sH[i * 64 + k];
        sR[o * 64 + k] = fmaxf(acc, 0.f);
    }
    __syncthreads();
    if (t < 192) {
        int o = t % 3;
        int kk = t / 3;
        float acc = b4[o];
        const float* wr = w4 + o * 64;
        for (int i = 0; i < 64; i++) acc += wr[i] * sR[i * 64 + kk];
        out[((size_t)b * KK_ + kk) * 3 + o] = acc;
    }
}

// ---------------------------------------------------------------------------
extern "C" void kernel_launch(void* const* d_in, const int* in_sizes, int n_in,
                              void* d_out, int out_size, void* d_ws, size_t ws_size,
                              hipStream_t stream) {
    const float* X    = (const float*)d_in[0];
    const float* gf   = (const float*)d_in[1];
    const float* ps1w = (const float*)d_in[2];
    const float* ps1b = (const float*)d_in[3];
    const float* w1   = (const float*)d_in[4];
    const float* b1   = (const float*)d_in[5];
    const float* w2   = (const float*)d_in[6];
    const float* b2   = (const float*)d_in[7];
    const float* wsc  = (const float*)d_in[8];
    const float* bscp = (const float*)d_in[9];
    const float* w3   = (const float*)d_in[10];
    const float* b3   = (const float*)d_in[11];
    const float* w4   = (const float*)d_in[12];
    const float* b4   = (const float*)d_in[13];
    float* out = (float*)d_out;

    const size_t G_PER  = (size_t)NN_ * NN_ * 4;         // 16 MB / batch
    const size_t XC_PER = (size_t)32 * NN_ * 128;        // 8 MB / batch
    const size_t IDX_B  = (size_t)BB_ * KK_ * 4;
    const size_t CAT_B  = (size_t)BB_ * 2176 * KK_ * 4;  // 17.8 MB
    const size_t T1_B   = (size_t)BB_ * 128 * KK_ * 4;   // 1 MB
    size_t rest = IDX_B + CAT_B + 2 * T1_B;

    // ws ladder: prefer gs=8 with double-buffered G (merged fps hiding)
    int gs = 1; int merged = 0;
    {
        const int cand_gs[8]  = {8, 8, 4, 4, 2, 2, 1, 1};
        const int cand_m[8]   = {1, 0, 1, 0, 1, 0, 1, 0};
        for (int i = 0; i < 8; i++) {
            size_t need = (size_t)(cand_m[i] ? 2 : 1) * cand_gs[i] * G_PER
                        + (size_t)cand_gs[i] * XC_PER + rest;
            if (ws_size >= need) { gs = cand_gs[i]; merged = cand_m[i]; break; }
        }
    }

    char* ws = (char*)d_ws;
    float* Gbuf = (float*)ws;
    size_t gBufBytes = (size_t)(merged ? 2 : 1) * gs * G_PER;
    unsigned char* Xc = (unsigned char*)(ws + gBufBytes);
    char* p = (char*)Xc + (size_t)gs * XC_PER;
    int* idxws = (int*)p;    p += IDX_B;
    float* cat = (float*)p;  p += CAT_B;
    float* t1  = (float*)p;  p += T1_B;
    float* sc  = (float*)p;

    int ng = BB_ / gs;
    size_t halfElems = (size_t)gs * NN_ * NN_;
    for (int g = 0; g < ng; g++) {
        int g0 = g * gs;
        convert_kernel<<<dim3(NN_ / 256, 32, gs), 256, 0, stream>>>(X, Xc, g0);
        float* Gcur = Gbuf + (merged ? (size_t)(g & 1) * halfElems : 0);
        if (merged) {
            float* Gprev = Gbuf + (size_t)((g & 1) ^ 1) * halfElems;
            int nFps = (g > 0) ? gs : 0;
            gram_fps_kernel<<<nFps + gs * 256, 256, 0, stream>>>(
                Xc, Gcur, Gprev, idxws, nFps, g0 - gs);
        } else {
            gram_fps_kernel<<<gs * 256, 256, 0, stream>>>(Xc, Gcur, Gcur, idxws, 0, 0);
            gram_fps_kernel<<<gs, 256, 0, stream>>>(Xc, Gcur, Gcur, idxws, gs, g0);
        }
    }
    int nFpsLast = merged ? gs : 0;
    float* Glast = Gbuf + (merged ? (size_t)((ng - 1) & 1) * halfElems : 0);
    x1_fps_kernel<<<nFpsLast + 128, 256, 0, stream>>>(
        gf, ps1w, ps1b, cat, Glast, idxws, BB_ - gs, nFpsLast);
    catfill_kernel<<<dim3(512, BB_), 256, 0, stream>>>(X, gf, idxws, cat);
    mlp1_kernel<<<dim3(32, BB_), 256, 0, stream>>>(cat, w1, b1, wsc, bscp, t1, sc);
    mlp2_kernel<<<BB_, 256, 0, stream>>>(t1, sc, w2, b2, w3, b3, w4, b4, out);
}

// Round 3
// 1583.554 us; speedup vs baseline: 1.5131x; 1.1110x over previous
//
#include <hip/hip_runtime.h>

// Problem constants: B=32, C=1024, N=2048, K=64
#define BB_ 32
#define CC_ 1024
#define NN_ 2048
#define KK_ 64

typedef __bf16 bf16x8 __attribute__((ext_vector_type(8)));
typedef __bf16 bf16x2 __attribute__((ext_vector_type(2)));
typedef float f32x4 __attribute__((ext_vector_type(4)));
typedef unsigned int u32;

__device__ inline unsigned short f2bf_rn(float f) {
    unsigned u = __float_as_uint(f);
    unsigned r = (u + 0x7fffu + ((u >> 16) & 1u)) >> 16;
    return (unsigned short)r;
}

__device__ inline unsigned pack_bf16_rn(float f0, float f1) {
#if __has_builtin(__builtin_amdgcn_cvt_pk_bf16_f32)
    union { bf16x2 v; unsigned u; } x;
    x.v = __builtin_amdgcn_cvt_pk_bf16_f32(f0, f1);
    return x.u;
#else
    return (unsigned)f2bf_rn(f0) | ((unsigned)f2bf_rn(f1) << 16);
#endif
}

__device__ inline void gload16(const void* g, void* l) {
    __builtin_amdgcn_global_load_lds(
        (const __attribute__((address_space(1))) u32*)g,
        (__attribute__((address_space(3))) u32*)l, 16, 0, 0);
}

// ---------------------------------------------------------------------------
// convert: X (fp32, B,C,N) -> Xc split-bf16, per group.
// Layout: Xc[lb][kt][n] is 128 B: 8 chunks of 16 B (8 bf16).
// Chunk for term t (0=hi,1=lo), k-quad q sits at position p = (4t+q) ^ (n&7).
// grid (8, 32, gs) x 256
// ---------------------------------------------------------------------------
__global__ void convert_kernel(const float* __restrict__ X,
                               unsigned char* __restrict__ Xc, int g0) {
    int lb = blockIdx.z, kt = blockIdx.y;
    int n = blockIdx.x * 256 + threadIdx.x;
    int b = g0 + lb;
    const float* Xb = X + (size_t)b * CC_ * NN_;
    unsigned char* dst = Xc + (((size_t)lb * 32 + kt) * NN_ + n) * 128;
    int sw = n & 7;
#pragma unroll
    for (int q = 0; q < 4; q++) {
        float f[8];
#pragma unroll
        for (int j = 0; j < 8; j++)
            f[j] = Xb[(size_t)(kt * 32 + q * 8 + j) * NN_ + n];
        union { unsigned u[4]; uint4 v; } hq, lq;
#pragma unroll
        for (int j2 = 0; j2 < 4; j2++) {
            float a = f[2 * j2], c = f[2 * j2 + 1];
            unsigned hp = pack_bf16_rn(a, c);
            float h0f = __uint_as_float((hp & 0xffffu) << 16);
            float h1f = __uint_as_float(hp & 0xffff0000u);
            hq.u[j2] = hp;
            lq.u[j2] = pack_bf16_rn(a - h0f, c - h1f);
        }
        int p = q ^ sw;
        *(uint4*)(dst + (p << 4)) = hq.v;
        *(uint4*)(dst + ((p ^ 4) << 4)) = lq.v;
    }
}

// ---------------------------------------------------------------------------
// fps block body: one block = one batch; 63 sequential min-update+argmax steps
// over G rows. Norms from diag(G). Tie -> lower index (numpy argmax).
// ---------------------------------------------------------------------------
__device__ void fps_block(const float* Gb, int* idx, int b) {
    __shared__ float swv[2][4];
    __shared__ int swi[2][4];
    int t = threadIdx.x;
    float dist[8], nr[8];
#pragma unroll
    for (int r = 0; r < 8; r++) {
        nr[r] = Gb[(size_t)(t + 256 * r) * (NN_ + 1)];
        dist[r] = 1e10f;
    }
    if (t == 0) idx[b * KK_] = 0;
    int far = 0;
    for (int k = 1; k < KK_; k++) {
        float nf = Gb[(size_t)far * (NN_ + 1)];
        const float* grow = Gb + (size_t)far * NN_;
        float v = -1.f;
        int pi = 0;
#pragma unroll
        for (int r = 0; r < 8; r++) {
            float d = nr[r] + nf - 2.f * grow[t + 256 * r];
            dist[r] = fminf(dist[r], d);
            if (dist[r] > v) { v = dist[r]; pi = t + 256 * r; }
        }
#pragma unroll
        for (int off = 32; off; off >>= 1) {
            float ov = __shfl_down(v, off);
            int oi = __shfl_down(pi, off);
            if (ov > v || (ov == v && oi < pi)) { v = ov; pi = oi; }
        }
        int par = k & 1;
        if ((t & 63) == 0) { swv[par][t >> 6] = v; swi[par][t >> 6] = pi; }
        __syncthreads();
        float bv = swv[par][0];
        int bi = swi[par][0];
#pragma unroll
        for (int ww = 1; ww < 4; ww++) {
            float wv2 = swv[par][ww]; int wi2 = swi[par][ww];
            if (wv2 > bv || (wv2 == bv && wi2 < bi)) { bv = wv2; bi = wi2; }
        }
        far = bi;
        if (t == 0) idx[b * KK_ + k] = bi;
    }
}

// ---------------------------------------------------------------------------
// gram (+merged fps): blocks [0,nFps) run fps on Gprev (resident from t=0);
// the rest compute G = X^T X via split-bf16 3-term MFMA with global_load_lds
// staging from the pre-converted swizzled Xc. gram part: gs*256 blocks.
// ---------------------------------------------------------------------------
__global__ __launch_bounds__(256, 2) void gram_fps_kernel(
    const unsigned char* __restrict__ Xc, float* __restrict__ G,
    const float* Gprev, int* __restrict__ idx, int nFps, int g0prev) {
    if ((int)blockIdx.x < nFps) {
        fps_block(Gprev + (size_t)blockIdx.x * NN_ * NN_, idx, g0prev + blockIdx.x);
        return;
    }
    int bx = blockIdx.x - nFps;
    int lb = bx >> 8;
    int tile = bx & 255;
    int tm = tile & 15, tn = tile >> 4;
    int t = threadIdx.x;
    __shared__ __align__(16) unsigned char sA[16384];
    __shared__ __align__(16) unsigned char sB[16384];

    const unsigned char* XcB = Xc + (size_t)lb * 32 * NN_ * 128;
    int w = t >> 6, l = t & 63;
    int m0w = (w & 1) * 64, n0w = (w >> 1) * 64;
    int q = l >> 4, rr = l & 15;

    f32x4 zero = {0.f, 0.f, 0.f, 0.f};
    f32x4 acc[4][4];
#pragma unroll
    for (int mt = 0; mt < 4; mt++)
#pragma unroll
        for (int nt = 0; nt < 4; nt++) acc[mt][nt] = zero;

    for (int kt = 0; kt < 32; kt++) {
        const unsigned char* Ab = XcB + ((size_t)kt * NN_ + (size_t)tm * 128) * 128;
        const unsigned char* Bb = XcB + ((size_t)kt * NN_ + (size_t)tn * 128) * 128;
        __syncthreads();
#pragma unroll
        for (int r = 0; r < 4; r++) {
            gload16(Ab + r * 4096 + t * 16, sA + r * 4096 + t * 16);
            gload16(Bb + r * 4096 + t * 16, sB + r * 4096 + t * 16);
        }
        __syncthreads();

        bf16x8 ah[4], al[4], bh[4], bl[4];
#pragma unroll
        for (int mt = 0; mt < 4; mt++) {
            int ra = m0w + mt * 16 + rr;
            int pa = q ^ (ra & 7);
            ah[mt] = *(const bf16x8*)(sA + ra * 128 + (pa << 4));
            al[mt] = *(const bf16x8*)(sA + ra * 128 + ((pa ^ 4) << 4));
            int rb = n0w + mt * 16 + rr;
            int pb = q ^ (rb & 7);
            bh[mt] = *(const bf16x8*)(sB + rb * 128 + (pb << 4));
            bl[mt] = *(const bf16x8*)(sB + rb * 128 + ((pb ^ 4) << 4));
        }
#pragma unroll
        for (int mt = 0; mt < 4; mt++)
#pragma unroll
            for (int nt = 0; nt < 4; nt++) {
                acc[mt][nt] = __builtin_amdgcn_mfma_f32_16x16x32_bf16(ah[mt], bh[nt], acc[mt][nt], 0, 0, 0);
                acc[mt][nt] = __builtin_amdgcn_mfma_f32_16x16x32_bf16(ah[mt], bl[nt], acc[mt][nt], 0, 0, 0);
                acc[mt][nt] = __builtin_amdgcn_mfma_f32_16x16x32_bf16(al[mt], bh[nt], acc[mt][nt], 0, 0, 0);
            }
    }

    float* Gb = G + (size_t)lb * NN_ * NN_;
    int i0 = tm * 128, j0 = tn * 128;
    int cc = l & 15;
#pragma unroll
    for (int mt = 0; mt < 4; mt++)
#pragma unroll
        for (int nt = 0; nt < 4; nt++)
#pragma unroll
            for (int r = 0; r < 4; r++) {
                int gi = i0 + m0w + mt * 16 + q * 4 + r;
                int gj = j0 + n0w + nt * 16 + cc;
                Gb[(size_t)gi * NN_ + gj] = acc[mt][nt][r];
            }
}

// ---------------------------------------------------------------------------
// x1 (+merged last fps): blocks [0,nFps) run fps; rest compute
// cat[b][o][k] = sum_i gf[b][i]*ps1_w[i][o][k] + ps1_b[o], o in [0,128).
// ---------------------------------------------------------------------------
__global__ void x1_fps_kernel(const float* __restrict__ gf, const float* __restrict__ w,
                              const float* __restrict__ bias, float* __restrict__ cat,
                              const float* Gprev, int* __restrict__ idx,
                              int g0prev, int nFps) {
    if ((int)blockIdx.x < nFps) {
        fps_block(Gprev + (size_t)blockIdx.x * NN_ * NN_, idx, g0prev + blockIdx.x);
        return;
    }
    int bid = blockIdx.x - nFps;
    int t = threadIdx.x;
    int okg = bid & 31, bg = bid >> 5;
    int ok = okg * 256 + t;
    int o = ok >> 6, k = ok & 63;
    float acc[8];
#pragma unroll
    for (int j = 0; j < 8; j++) acc[j] = 0.f;
    const float* g = gf + (size_t)(bg * 8) * CC_;
    for (int i = 0; i < CC_; i++) {
        float wv = w[(size_t)(i * 128 + o) * KK_ + k];
#pragma unroll
        for (int j = 0; j < 8; j++) acc[j] += g[j * CC_ + i] * wv;
    }
    float bv = bias[o];
#pragma unroll
    for (int j = 0; j < 8; j++)
        cat[((size_t)(bg * 8 + j) * 2176 + o) * KK_ + k] = acc[j] + bv;
}

// ---------------------------------------------------------------------------
// catfill: channels [128,1152) = gathered point features; [1152,2176) = gf
// grid (512, 32) x 256
// ---------------------------------------------------------------------------
__global__ void catfill_kernel(const float* __restrict__ X, const float* __restrict__ gf,
                               const int* __restrict__ idx, float* __restrict__ cat) {
    int b = blockIdx.y;
    int t = threadIdx.x;
    int ch = 128 + blockIdx.x * 4 + (t >> 6);
    int k = t & 63;
    float v;
    if (ch < 1152) {
        int c = ch - 128;
        int ik = idx[b * KK_ + k];
        v = X[((size_t)b * CC_ + c) * NN_ + ik];
    } else {
        v = gf[b * CC_ + (ch - 1152)];
    }
    cat[((size_t)b * 2176 + ch) * KK_ + k] = v;
}

// ---------------------------------------------------------------------------
// mlp1: t1 = relu(m1c1@cat + b1), sc = m1sc@cat + bsc.  grid (32,32) x 256
// ---------------------------------------------------------------------------
__global__ void mlp1_kernel(const float* __restrict__ cat, const float* __restrict__ w1,
                            const float* __restrict__ b1, const float* __restrict__ wsc,
                            const float* __restrict__ bsc, float* __restrict__ t1,
                            float* __restrict__ sc) {
    int b = blockIdx.y;
    int og = blockIdx.x;
    int t = threadIdx.x;
    int o = og * 4 + (t >> 6);
    int k = t & 63;
    const float* cb = cat + (size_t)b * 2176 * KK_;
    const float* wr1 = w1 + (size_t)o * 2176;
    const float* wrs = wsc + (size_t)o * 2176;
    float a1 = 0.f, a2 = 0.f;
    for (int i = 0; i < 2176; i++) {
        float cv = cb[i * KK_ + k];
        a1 += wr1[i] * cv;
        a2 += wrs[i] * cv;
    }
    size_t oidx = ((size_t)b * 128 + o) * KK_ + k;
    t1[oidx] = fmaxf(a1 + b1[o], 0.f);
    sc[oidx] = a2 + bsc[o];
}

// ---------------------------------------------------------------------------
// mlp2 (ILP rewrite): h = m1c2@t1 + b2 + sc; r2 = relu(m2c1@h + b3);
// out = (m2c2@r2 + b4)^T. One block per batch. Each thread owns 8 independent
// accumulator chains per pass; one LDS read feeds 8 FMAs; weights are
// wave-uniform float4 (s_load_dwordx4). grid (32) x 256
// ---------------------------------------------------------------------------
__global__ void mlp2_kernel(const float* __restrict__ t1, const float* __restrict__ sc,
                            const float* __restrict__ w2, const float* __restrict__ b2,
                            const float* __restrict__ w3, const float* __restrict__ b3,
                            const float* __restrict__ w4, const float* __restrict__ b4,
                            float* __restrict__ out) {
    __shared__ float sT[128 * 64];
    __shared__ float sH[128 * 64];
    __shared__ float sR[64 * 64];
    int b = blockIdx.x, t = threadIdx.x;
    const float4* t1b4 = (const float4*)(t1 + (size_t)b * 8192);
    for (int j = t; j < 2048; j += 256) ((float4*)sT)[j] = t1b4[j];
    __syncthreads();
    int k = t & 63, og = t >> 6;
    const float* scb = sc + (size_t)b * 8192;

    // phase 1: h[o][k], o in [og*32, og*32+32), 8 rows per pass
#pragma unroll
    for (int pass = 0; pass < 4; pass++) {
        int o0 = og * 32 + pass * 8;
        float acc[8];
#pragma unroll
        for (int j = 0; j < 8; j++) acc[j] = b2[o0 + j] + scb[(o0 + j) * 64 + k];
        for (int i4 = 0; i4 < 32; i4++) {
            float v0 = sT[(i4 * 4 + 0) * 64 + k];
            float v1 = sT[(i4 * 4 + 1) * 64 + k];
            float v2 = sT[(i4 * 4 + 2) * 64 + k];
            float v3 = sT[(i4 * 4 + 3) * 64 + k];
#pragma unroll
            for (int j = 0; j < 8; j++) {
                float4 wv = *(const float4*)(w2 + (size_t)(o0 + j) * 128 + i4 * 4);
                acc[j] += wv.x * v0 + wv.y * v1 + wv.z * v2 + wv.w * v3;
            }
        }
#pragma unroll
        for (int j = 0; j < 8; j++) sH[(o0 + j) * 64 + k] = acc[j];
    }
    __syncthreads();

    // phase 2: r2[o][k], o in [og*16, og*16+16), 8 rows per pass
#pragma unroll
    for (int pass = 0; pass < 2; pass++) {
        int o0 = og * 16 + pass * 8;
        float acc[8];
#pragma unroll
        for (int j = 0; j < 8; j++) acc[j] = b3[o0 + j];
        for (int i4 = 0; i4 < 32; i4++) {
            float v0 = sH[(i4 * 4 + 0) * 64 + k];
            float v1 = sH[(i4 * 4 + 1) * 64 + k];
            float v2 = sH[(i4 * 4 + 2) * 64 + k];
            float v3 = sH[(i4 * 4 + 3) * 64 + k];
#pragma unroll
            for (int j = 0; j < 8; j++) {
                float4 wv = *(const float4*)(w3 + (size_t)(o0 + j) * 128 + i4 * 4);
                acc[j] += wv.x * v0 + wv.y * v1 + wv.z * v2 + wv.w * v3;
            }
        }
#pragma unroll
        for (int j = 0; j < 8; j++) sR[(o0 + j) * 64 + k] = fmaxf(acc[j], 0.f);
    }
    __syncthreads();

    // phase 3: out[k][o], o in {0,1,2}
    if (t < 192) {
        int o = t % 3;
        int kk = t / 3;
        float a0 = 0.f, a1 = 0.f, a2 = 0.f, a3 = 0.f;
        for (int i4 = 0; i4 < 16; i4++) {
            float4 wv = *(const float4*)(w4 + o * 64 + i4 * 4);
            a0 += wv.x * sR[(i4 * 4 + 0) * 64 + kk];
            a1 += wv.y * sR[(i4 * 4 + 1) * 64 + kk];
            a2 += wv.z * sR[(i4 * 4 + 2) * 64 + kk];
            a3 += wv.w * sR[(i4 * 4 + 3) * 64 + kk];
        }
        out[((size_t)b * KK_ + kk) * 3 + o] = b4[o] + ((a0 + a1) + (a2 + a3));
    }
}

// ---------------------------------------------------------------------------
extern "C" void kernel_launch(void* const* d_in, const int* in_sizes, int n_in,
                              void* d_out, int out_size, void* d_ws, size_t ws_size,
                              hipStream_t stream) {
    const float* X    = (const float*)d_in[0];
    const float* gf   = (const float*)d_in[1];
    const float* ps1w = (const float*)d_in[2];
    const float* ps1b = (const float*)d_in[3];
    const float* w1   = (const float*)d_in[4];
    const float* b1   = (const float*)d_in[5];
    const float* w2   = (const float*)d_in[6];
    const float* b2   = (const float*)d_in[7];
    const float* wsc  = (const float*)d_in[8];
    const float* bscp = (const float*)d_in[9];
    const float* w3   = (const float*)d_in[10];
    const float* b3   = (const float*)d_in[11];
    const float* w4   = (const float*)d_in[12];
    const float* b4   = (const float*)d_in[13];
    float* out = (float*)d_out;

    const size_t G_PER  = (size_t)NN_ * NN_ * 4;         // 16 MB / batch
    const size_t XC_PER = (size_t)32 * NN_ * 128;        // 8 MB / batch
    const size_t IDX_B  = (size_t)BB_ * KK_ * 4;
    const size_t CAT_B  = (size_t)BB_ * 2176 * KK_ * 4;  // 17.8 MB
    const size_t T1_B   = (size_t)BB_ * 128 * KK_ * 4;   // 1 MB
    size_t rest = IDX_B + CAT_B + 2 * T1_B;

    // ws ladder: ALWAYS prefer merged (double-buffered G, fps hidden) over
    // larger-but-unmerged configs — exposed fps costs ~100 us per group.
    int gs = 1; int merged = 0;
    {
        const int cand_gs[8]  = {8, 4, 2, 1, 8, 4, 2, 1};
        const int cand_m[8]   = {1, 1, 1, 1, 0, 0, 0, 0};
        for (int i = 0; i < 8; i++) {
            size_t need = (size_t)(cand_m[i] ? 2 : 1) * cand_gs[i] * G_PER
                        + (size_t)cand_gs[i] * XC_PER + rest;
            if (ws_size >= need) { gs = cand_gs[i]; merged = cand_m[i]; break; }
        }
    }

    char* ws = (char*)d_ws;
    float* Gbuf = (float*)ws;
    size_t gBufBytes = (size_t)(merged ? 2 : 1) * gs * G_PER;
    unsigned char* Xc = (unsigned char*)(ws + gBufBytes);
    char* p = (char*)Xc + (size_t)gs * XC_PER;
    int* idxws = (int*)p;    p += IDX_B;
    float* cat = (float*)p;  p += CAT_B;
    float* t1  = (float*)p;  p += T1_B;
    float* sc  = (float*)p;

    int ng = BB_ / gs;
    size_t halfElems = (size_t)gs * NN_ * NN_;
    for (int g = 0; g < ng; g++) {
        int g0 = g * gs;
        convert_kernel<<<dim3(NN_ / 256, 32, gs), 256, 0, stream>>>(X, Xc, g0);
        float* Gcur = Gbuf + (merged ? (size_t)(g & 1) * halfElems : 0);
        if (merged) {
            float* Gprev = Gbuf + (size_t)((g & 1) ^ 1) * halfElems;
            int nFps = (g > 0) ? gs : 0;
            gram_fps_kernel<<<nFps + gs * 256, 256, 0, stream>>>(
                Xc, Gcur, Gprev, idxws, nFps, g0 - gs);
        } else {
            gram_fps_kernel<<<gs * 256, 256, 0, stream>>>(Xc, Gcur, Gcur, idxws, 0, 0);
            gram_fps_kernel<<<gs, 256, 0, stream>>>(Xc, Gcur, Gcur, idxws, gs, g0);
        }
    }
    int nFpsLast = merged ? gs : 0;
    float* Glast = Gbuf + (merged ? (size_t)((ng - 1) & 1) * halfElems : 0);
    x1_fps_kernel<<<nFpsLast + 128, 256, 0, stream>>>(
        gf, ps1w, ps1b, cat, Glast, idxws, BB_ - gs, nFpsLast);
    catfill_kernel<<<dim3(512, BB_), 256, 0, stream>>>(X, gf, idxws, cat);
    mlp1_kernel<<<dim3(32, BB_), 256, 0, stream>>>(cat, w1, b1, wsc, bscp, t1, sc);
    mlp2_kernel<<<BB_, 256, 0, stream>>>(t1, sc, w2, b2, w3, b3, w4, b4, out);
}

// Round 4
// 1450.258 us; speedup vs baseline: 1.6521x; 1.0919x over previous
//
#include <hip/hip_runtime.h>

// Problem constants: B=32, C=1024, N=2048, K=64
#define BB_ 32
#define CC_ 1024
#define NN_ 2048
#define KK_ 64

typedef __bf16 bf16x8 __attribute__((ext_vector_type(8)));
typedef __bf16 bf16x2 __attribute__((ext_vector_type(2)));
typedef float f32x4 __attribute__((ext_vector_type(4)));
typedef unsigned int u32;

__device__ inline unsigned short f2bf_rn(float f) {
    unsigned u = __float_as_uint(f);
    unsigned r = (u + 0x7fffu + ((u >> 16) & 1u)) >> 16;
    return (unsigned short)r;
}

__device__ inline unsigned pack_bf16_rn(float f0, float f1) {
#if __has_builtin(__builtin_amdgcn_cvt_pk_bf16_f32)
    union { bf16x2 v; unsigned u; } x;
    x.v = __builtin_amdgcn_cvt_pk_bf16_f32(f0, f1);
    return x.u;
#else
    return (unsigned)f2bf_rn(f0) | ((unsigned)f2bf_rn(f1) << 16);
#endif
}

__device__ inline void gload16(const void* g, void* l) {
    __builtin_amdgcn_global_load_lds(
        (const __attribute__((address_space(1))) u32*)g,
        (__attribute__((address_space(3))) u32*)l, 16, 0, 0);
}

// ---------------------------------------------------------------------------
// convert body: X (fp32) -> Xc split-bf16 swizzled. One "cid" = 256 columns
// of one (lb, kt). Layout per (lb,kt,n): 128 B = 8 chunks of 16 B; chunk for
// term tmr (0=hi,1=lo), k-quad q at position (4*tmr+q) ^ (n&7).
// ---------------------------------------------------------------------------
__device__ void convert_body(const float* __restrict__ X,
                             unsigned char* __restrict__ Xc, int g0,
                             int cid, int t) {
    int chunk = cid & 7;
    int kt = (cid >> 3) & 31;
    int lb = cid >> 8;
    int n = chunk * 256 + t;
    int b = g0 + lb;
    const float* Xb = X + (size_t)b * CC_ * NN_;
    unsigned char* dst = Xc + (((size_t)lb * 32 + kt) * NN_ + n) * 128;
    int sw = n & 7;
#pragma unroll
    for (int q = 0; q < 4; q++) {
        float f[8];
#pragma unroll
        for (int j = 0; j < 8; j++)
            f[j] = Xb[(size_t)(kt * 32 + q * 8 + j) * NN_ + n];
        union { unsigned u[4]; uint4 v; } hq, lq;
#pragma unroll
        for (int j2 = 0; j2 < 4; j2++) {
            float a = f[2 * j2], c = f[2 * j2 + 1];
            unsigned hp = pack_bf16_rn(a, c);
            float h0f = __uint_as_float((hp & 0xffffu) << 16);
            float h1f = __uint_as_float(hp & 0xffff0000u);
            hq.u[j2] = hp;
            lq.u[j2] = pack_bf16_rn(a - h0f, c - h1f);
        }
        int p = q ^ sw;
        *(uint4*)(dst + (p << 4)) = hq.v;
        *(uint4*)(dst + ((p ^ 4) << 4)) = lq.v;
    }
}

__global__ void convert_kernel(const float* __restrict__ X,
                               unsigned char* __restrict__ Xc, int g0) {
    convert_body(X, Xc, g0, blockIdx.x, threadIdx.x);
}

// ---------------------------------------------------------------------------
// fps block body: one block = one batch; 63 sequential min-update+argmax steps
// over G rows. Norms from diag(G). Tie -> lower index (numpy argmax).
// ---------------------------------------------------------------------------
__device__ void fps_block(const float* Gb, int* idx, int b) {
    __shared__ float swv[2][4];
    __shared__ int swi[2][4];
    int t = threadIdx.x;
    float dist[8], nr[8];
#pragma unroll
    for (int r = 0; r < 8; r++) {
        nr[r] = Gb[(size_t)(t + 256 * r) * (NN_ + 1)];
        dist[r] = 1e10f;
    }
    if (t == 0) idx[b * KK_] = 0;
    int far = 0;
    for (int k = 1; k < KK_; k++) {
        float nf = Gb[(size_t)far * (NN_ + 1)];
        const float* grow = Gb + (size_t)far * NN_;
        float v = -1.f;
        int pi = 0;
#pragma unroll
        for (int r = 0; r < 8; r++) {
            float d = nr[r] + nf - 2.f * grow[t + 256 * r];
            dist[r] = fminf(dist[r], d);
            if (dist[r] > v) { v = dist[r]; pi = t + 256 * r; }
        }
#pragma unroll
        for (int off = 32; off; off >>= 1) {
            float ov = __shfl_down(v, off);
            int oi = __shfl_down(pi, off);
            if (ov > v || (ov == v && oi < pi)) { v = ov; pi = oi; }
        }
        int par = k & 1;
        if ((t & 63) == 0) { swv[par][t >> 6] = v; swi[par][t >> 6] = pi; }
        __syncthreads();
        float bv = swv[par][0];
        int bi = swi[par][0];
#pragma unroll
        for (int ww = 1; ww < 4; ww++) {
            float wv2 = swv[par][ww]; int wi2 = swi[par][ww];
            if (wv2 > bv || (wv2 == bv && wi2 < bi)) { bv = wv2; bi = wi2; }
        }
        far = bi;
        if (t == 0) idx[b * KK_ + k] = bi;
    }
}

// ---------------------------------------------------------------------------
// gram (+merged fps +merged convert-of-next-group):
//  blocks [0,nFps)                -> fps on Gprev
//  blocks [nFps, nFps+gs*136)     -> triangular gram tiles (G symmetric!)
//  blocks [nFps+gs*136, +nConv)   -> convert group g+1 into XcNext
// ---------------------------------------------------------------------------
__global__ __launch_bounds__(256, 2) void gram_fps_kernel(
    const unsigned char* __restrict__ Xc, float* __restrict__ G,
    const float* Gprev, int* __restrict__ idx, int nFps, int g0prev,
    const float* __restrict__ X, unsigned char* __restrict__ XcNext,
    int g0next, int nGram) {
    int bx = (int)blockIdx.x;
    if (bx < nFps) {
        fps_block(Gprev + (size_t)bx * NN_ * NN_, idx, g0prev + bx);
        return;
    }
    bx -= nFps;
    if (bx >= nGram) {
        convert_body(X, XcNext, g0next, bx - nGram, threadIdx.x);
        return;
    }
    int lb = bx / 136;
    int tt = bx - lb * 136;
    int tn = (int)((sqrtf(8.f * tt + 1.f) - 1.f) * 0.5f);
    while ((tn + 1) * (tn + 2) / 2 <= tt) tn++;
    while (tn * (tn + 1) / 2 > tt) tn--;
    int tm = tt - tn * (tn + 1) / 2;      // tm <= tn
    bool diag = (tm == tn);
    int t = threadIdx.x;
    __shared__ __align__(16) unsigned char sA[16384];
    __shared__ __align__(16) unsigned char sB[16384];

    const unsigned char* XcB = Xc + (size_t)lb * 32 * NN_ * 128;
    int w = t >> 6, l = t & 63;
    int m0w = (w & 1) * 64, n0w = (w >> 1) * 64;
    int q = l >> 4, rr = l & 15;

    f32x4 zero = {0.f, 0.f, 0.f, 0.f};
    f32x4 acc[4][4];
#pragma unroll
    for (int mt = 0; mt < 4; mt++)
#pragma unroll
        for (int nt = 0; nt < 4; nt++) acc[mt][nt] = zero;

    const unsigned char* sBp = diag ? sA : sB;
    for (int kt = 0; kt < 32; kt++) {
        const unsigned char* Ab = XcB + ((size_t)kt * NN_ + (size_t)tm * 128) * 128;
        const unsigned char* Bb = XcB + ((size_t)kt * NN_ + (size_t)tn * 128) * 128;
        __syncthreads();
#pragma unroll
        for (int r = 0; r < 4; r++)
            gload16(Ab + r * 4096 + t * 16, sA + r * 4096 + t * 16);
        if (!diag) {
#pragma unroll
            for (int r = 0; r < 4; r++)
                gload16(Bb + r * 4096 + t * 16, sB + r * 4096 + t * 16);
        }
        __syncthreads();

        bf16x8 ah[4], al[4], bh[4], bl[4];
#pragma unroll
        for (int mt = 0; mt < 4; mt++) {
            int ra = m0w + mt * 16 + rr;
            int pa = q ^ (ra & 7);
            ah[mt] = *(const bf16x8*)(sA + ra * 128 + (pa << 4));
            al[mt] = *(const bf16x8*)(sA + ra * 128 + ((pa ^ 4) << 4));
            int rb = n0w + mt * 16 + rr;
            int pb = q ^ (rb & 7);
            bh[mt] = *(const bf16x8*)(sBp + rb * 128 + (pb << 4));
            bl[mt] = *(const bf16x8*)(sBp + rb * 128 + ((pb ^ 4) << 4));
        }
#pragma unroll
        for (int mt = 0; mt < 4; mt++)
#pragma unroll
            for (int nt = 0; nt < 4; nt++) {
                acc[mt][nt] = __builtin_amdgcn_mfma_f32_16x16x32_bf16(ah[mt], bh[nt], acc[mt][nt], 0, 0, 0);
                acc[mt][nt] = __builtin_amdgcn_mfma_f32_16x16x32_bf16(ah[mt], bl[nt], acc[mt][nt], 0, 0, 0);
                acc[mt][nt] = __builtin_amdgcn_mfma_f32_16x16x32_bf16(al[mt], bh[nt], acc[mt][nt], 0, 0, 0);
            }
    }

    // epilogue: C/D layout col=lane&15, row=(lane>>4)*4+reg; mirror for j<i
    float* Gb = G + (size_t)lb * NN_ * NN_;
    int i0 = tm * 128, j0 = tn * 128;
    int cc = l & 15;
#pragma unroll
    for (int mt = 0; mt < 4; mt++)
#pragma unroll
        for (int nt = 0; nt < 4; nt++)
#pragma unroll
            for (int r = 0; r < 4; r++) {
                int gi = i0 + m0w + mt * 16 + q * 4 + r;
                int gj = j0 + n0w + nt * 16 + cc;
                float val = acc[mt][nt][r];
                Gb[(size_t)gi * NN_ + gj] = val;
                if (!diag) Gb[(size_t)gj * NN_ + gi] = val;
            }
}

// ---------------------------------------------------------------------------
// x1 (+merged last fps): blocks [0,nFps) run fps; rest compute
// cat[b][o][k] = sum_i gf[b][i]*ps1_w[i][o][k] + ps1_b[o], o in [0,128).
// ---------------------------------------------------------------------------
__global__ void x1_fps_kernel(const float* __restrict__ gf, const float* __restrict__ w,
                              const float* __restrict__ bias, float* __restrict__ cat,
                              const float* Gprev, int* __restrict__ idx,
                              int g0prev, int nFps) {
    if ((int)blockIdx.x < nFps) {
        fps_block(Gprev + (size_t)blockIdx.x * NN_ * NN_, idx, g0prev + blockIdx.x);
        return;
    }
    int bid = blockIdx.x - nFps;
    int t = threadIdx.x;
    int okg = bid & 31, bg = bid >> 5;
    int ok = okg * 256 + t;
    int o = ok >> 6, k = ok & 63;
    float acc[8];
#pragma unroll
    for (int j = 0; j < 8; j++) acc[j] = 0.f;
    const float* g = gf + (size_t)(bg * 8) * CC_;
    for (int i = 0; i < CC_; i++) {
        float wv = w[(size_t)(i * 128 + o) * KK_ + k];
#pragma unroll
        for (int j = 0; j < 8; j++) acc[j] += g[j * CC_ + i] * wv;
    }
    float bv = bias[o];
#pragma unroll
    for (int j = 0; j < 8; j++)
        cat[((size_t)(bg * 8 + j) * 2176 + o) * KK_ + k] = acc[j] + bv;
}

// ---------------------------------------------------------------------------
// catfill: channels [128,1152) = gathered point features; [1152,2176) = gf
// grid (512, 32) x 256
// ---------------------------------------------------------------------------
__global__ void catfill_kernel(const float* __restrict__ X, const float* __restrict__ gf,
                               const int* __restrict__ idx, float* __restrict__ cat) {
    int b = blockIdx.y;
    int t = threadIdx.x;
    int ch = 128 + blockIdx.x * 4 + (t >> 6);
    int k = t & 63;
    float v;
    if (ch < 1152) {
        int c = ch - 128;
        int ik = idx[b * KK_ + k];
        v = X[((size_t)b * CC_ + c) * NN_ + ik];
    } else {
        v = gf[b * CC_ + (ch - 1152)];
    }
    cat[((size_t)b * 2176 + ch) * KK_ + k] = v;
}

// ---------------------------------------------------------------------------
// mlp1 (ILP rewrite): t1 = relu(m1c1@cat+b1), sc = m1sc@cat+bsc.
// block = (og, b): 8 outputs x both matrices; 256 threads = 64 k x 4 i-ranges.
// 16 independent acc chains/thread, wave-uniform float4 weight loads,
// LDS reduction across the 4 i-ranges. grid (16, 32) x 256
// ---------------------------------------------------------------------------
__global__ void mlp1_kernel(const float* __restrict__ cat, const float* __restrict__ w1,
                            const float* __restrict__ b1, const float* __restrict__ wsc,
                            const float* __restrict__ bsc, float* __restrict__ t1,
                            float* __restrict__ sc) {
    __shared__ float red[2][32][64];
    int b = blockIdx.y, og = blockIdx.x;
    int t = threadIdx.x;
    int k = t & 63, sub = t >> 6;
    int o0 = og * 8;
    const float* cb = cat + (size_t)b * 2176 * KK_;
    float a1[8], a2[8];
#pragma unroll
    for (int j = 0; j < 8; j++) { a1[j] = 0.f; a2[j] = 0.f; }
    int iBeg = sub * 544;
    for (int i = iBeg; i < iBeg + 544; i += 4) {
        float v0 = cb[(i + 0) * KK_ + k];
        float v1 = cb[(i + 1) * KK_ + k];
        float v2 = cb[(i + 2) * KK_ + k];
        float v3 = cb[(i + 3) * KK_ + k];
#pragma unroll
        for (int j = 0; j < 8; j++) {
            float4 wv = *(const float4*)(w1 + (size_t)(o0 + j) * 2176 + i);
            a1[j] += wv.x * v0 + wv.y * v1 + wv.z * v2 + wv.w * v3;
            float4 ws = *(const float4*)(wsc + (size_t)(o0 + j) * 2176 + i);
            a2[j] += ws.x * v0 + ws.y * v1 + ws.z * v2 + ws.w * v3;
        }
    }
#pragma unroll
    for (int j = 0; j < 8; j++) {
        red[0][sub * 8 + j][k] = a1[j];
        red[1][sub * 8 + j][k] = a2[j];
    }
    __syncthreads();
    // 2 matrices x 8 j x 64 k = 1024 outputs; 4 per thread
#pragma unroll
    for (int p = t; p < 1024; p += 256) {
        int m = p >> 9;
        int j = (p >> 6) & 7;
        int kk = p & 63;
        float s = red[m][j][kk] + red[m][8 + j][kk] + red[m][16 + j][kk] + red[m][24 + j][kk];
        int o = o0 + j;
        size_t oidx = ((size_t)b * 128 + o) * KK_ + kk;
        if (m == 0) t1[oidx] = fmaxf(s + b1[o], 0.f);
        else        sc[oidx] = s + bsc[o];
    }
}

// ---------------------------------------------------------------------------
// mlp2 (ILP): h = m1c2@t1 + b2 + sc; r2 = relu(m2c1@h + b3);
// out = (m2c2@r2 + b4)^T. grid (32) x 256
// ---------------------------------------------------------------------------
__global__ void mlp2_kernel(const float* __restrict__ t1, const float* __restrict__ sc,
                            const float* __restrict__ w2, const float* __restrict__ b2,
                            const float* __restrict__ w3, const float* __restrict__ b3,
                            const float* __restrict__ w4, const float* __restrict__ b4,
                            float* __restrict__ out) {
    __shared__ float sT[128 * 64];
    __shared__ float sH[128 * 64];
    __shared__ float sR[64 * 64];
    int b = blockIdx.x, t = threadIdx.x;
    const float4* t1b4 = (const float4*)(t1 + (size_t)b * 8192);
    for (int j = t; j < 2048; j += 256) ((float4*)sT)[j] = t1b4[j];
    __syncthreads();
    int k = t & 63, og = t >> 6;
    const float* scb = sc + (size_t)b * 8192;

#pragma unroll
    for (int pass = 0; pass < 4; pass++) {
        int o0 = og * 32 + pass * 8;
        float acc[8];
#pragma unroll
        for (int j = 0; j < 8; j++) acc[j] = b2[o0 + j] + scb[(o0 + j) * 64 + k];
        for (int i4 = 0; i4 < 32; i4++) {
            float v0 = sT[(i4 * 4 + 0) * 64 + k];
            float v1 = sT[(i4 * 4 + 1) * 64 + k];
            float v2 = sT[(i4 * 4 + 2) * 64 + k];
            float v3 = sT[(i4 * 4 + 3) * 64 + k];
#pragma unroll
            for (int j = 0; j < 8; j++) {
                float4 wv = *(const float4*)(w2 + (size_t)(o0 + j) * 128 + i4 * 4);
                acc[j] += wv.x * v0 + wv.y * v1 + wv.z * v2 + wv.w * v3;
            }
        }
#pragma unroll
        for (int j = 0; j < 8; j++) sH[(o0 + j) * 64 + k] = acc[j];
    }
    __syncthreads();

#pragma unroll
    for (int pass = 0; pass < 2; pass++) {
        int o0 = og * 16 + pass * 8;
        float acc[8];
#pragma unroll
        for (int j = 0; j < 8; j++) acc[j] = b3[o0 + j];
        for (int i4 = 0; i4 < 32; i4++) {
            float v0 = sH[(i4 * 4 + 0) * 64 + k];
            float v1 = sH[(i4 * 4 + 1) * 64 + k];
            float v2 = sH[(i4 * 4 + 2) * 64 + k];
            float v3 = sH[(i4 * 4 + 3) * 64 + k];
#pragma unroll
            for (int j = 0; j < 8; j++) {
                float4 wv = *(const float4*)(w3 + (size_t)(o0 + j) * 128 + i4 * 4);
                acc[j] += wv.x * v0 + wv.y * v1 + wv.z * v2 + wv.w * v3;
            }
        }
#pragma unroll
        for (int j = 0; j < 8; j++) sR[(o0 + j) * 64 + k] = fmaxf(acc[j], 0.f);
    }
    __syncthreads();

    if (t < 192) {
        int o = t % 3;
        int kk = t / 3;
        float a0 = 0.f, a1 = 0.f, a2 = 0.f, a3 = 0.f;
        for (int i4 = 0; i4 < 16; i4++) {
            float4 wv = *(const float4*)(w4 + o * 64 + i4 * 4);
            a0 += wv.x * sR[(i4 * 4 + 0) * 64 + kk];
            a1 += wv.y * sR[(i4 * 4 + 1) * 64 + kk];
            a2 += wv.z * sR[(i4 * 4 + 2) * 64 + kk];
            a3 += wv.w * sR[(i4 * 4 + 3) * 64 + kk];
        }
        out[((size_t)b * KK_ + kk) * 3 + o] = b4[o] + ((a0 + a1) + (a2 + a3));
    }
}

// ---------------------------------------------------------------------------
extern "C" void kernel_launch(void* const* d_in, const int* in_sizes, int n_in,
                              void* d_out, int out_size, void* d_ws, size_t ws_size,
                              hipStream_t stream) {
    const float* X    = (const float*)d_in[0];
    const float* gf   = (const float*)d_in[1];
    const float* ps1w = (const float*)d_in[2];
    const float* ps1b = (const float*)d_in[3];
    const float* w1   = (const float*)d_in[4];
    const float* b1   = (const float*)d_in[5];
    const float* w2   = (const float*)d_in[6];
    const float* b2   = (const float*)d_in[7];
    const float* wsc  = (const float*)d_in[8];
    const float* bscp = (const float*)d_in[9];
    const float* w3   = (const float*)d_in[10];
    const float* b3   = (const float*)d_in[11];
    const float* w4   = (const float*)d_in[12];
    const float* b4   = (const float*)d_in[13];
    float* out = (float*)d_out;

    const size_t G_PER  = (size_t)NN_ * NN_ * 4;         // 16 MB / batch
    const size_t XC_PER = (size_t)32 * NN_ * 128;        // 8 MB / batch
    const size_t IDX_B  = (size_t)BB_ * KK_ * 4;
    const size_t CAT_B  = (size_t)BB_ * 2176 * KK_ * 4;  // 17.8 MB
    const size_t T1_B   = (size_t)BB_ * 128 * KK_ * 4;   // 1 MB
    size_t rest = IDX_B + CAT_B + 2 * T1_B;

    // ws ladder: merged (fps hidden) preferred; pipe = convert hidden too.
    int gs = 1, merged = 0, pipe = 0;
    {
        const int tg[8]  = {8, 8, 4, 4, 2, 2, 1, 1};
        const int tmg[8] = {1, 1, 1, 1, 1, 1, 1, 0};
        const int tp[8]  = {1, 0, 1, 0, 1, 0, 0, 0};
        for (int i = 0; i < 8; i++) {
            size_t need = (size_t)(tmg[i] ? 2 : 1) * tg[i] * G_PER
                        + (size_t)(tp[i] ? 2 : 1) * tg[i] * XC_PER + rest;
            if (ws_size >= need) { gs = tg[i]; merged = tmg[i]; pipe = tp[i]; break; }
        }
    }

    char* ws = (char*)d_ws;
    float* Gbuf = (float*)ws;
    size_t gBufBytes = (size_t)(merged ? 2 : 1) * gs * G_PER;
    unsigned char* Xc0 = (unsigned char*)(ws + gBufBytes);
    unsigned char* Xc1 = Xc0 + (pipe ? (size_t)gs * XC_PER : 0);
    char* p = (char*)Xc0 + (size_t)(pipe ? 2 : 1) * gs * XC_PER;
    int* idxws = (int*)p;    p += IDX_B;
    float* cat = (float*)p;  p += CAT_B;
    float* t1  = (float*)p;  p += T1_B;
    float* sc  = (float*)p;

    int ng = BB_ / gs;
    size_t halfElems = (size_t)gs * NN_ * NN_;
    int nGram = gs * 136;
    int nConvAll = 256 * gs;

    if (pipe) convert_kernel<<<nConvAll, 256, 0, stream>>>(X, Xc0, 0);
    for (int g = 0; g < ng; g++) {
        int g0 = g * gs;
        unsigned char* Xcur  = (g & 1) ? Xc1 : Xc0;
        unsigned char* Xnext = (g & 1) ? Xc0 : Xc1;
        if (!pipe) {
            Xcur = Xc0;
            convert_kernel<<<nConvAll, 256, 0, stream>>>(X, Xc0, g0);
        }
        float* Gcur = Gbuf + (merged ? (size_t)(g & 1) * halfElems : 0);
        float* Gprev = Gbuf + (merged ? (size_t)((g & 1) ^ 1) * halfElems : 0);
        int nFps = (merged && g > 0) ? gs : 0;
        int nConv = (pipe && g < ng - 1) ? nConvAll : 0;
        gram_fps_kernel<<<nFps + nGram + nConv, 256, 0, stream>>>(
            Xcur, Gcur, Gprev, idxws, nFps, g0 - gs, X, Xnext, g0 + gs, nGram);
        if (!merged) {
            // exposed fps (smallest-ws fallback)
            gram_fps_kernel<<<gs, 256, 0, stream>>>(
                Xcur, Gcur, Gcur, idxws, gs, g0, X, Xnext, 0, 0);
        }
    }
    int nFpsLast = merged ? gs : 0;
    float* Glast = Gbuf + (merged ? (size_t)((ng - 1) & 1) * halfElems : 0);
    x1_fps_kernel<<<nFpsLast + 128, 256, 0, stream>>>(
        gf, ps1w, ps1b, cat, Glast, idxws, BB_ - gs, nFpsLast);
    catfill_kernel<<<dim3(512, BB_), 256, 0, stream>>>(X, gf, idxws, cat);
    mlp1_kernel<<<dim3(16, BB_), 256, 0, stream>>>(cat, w1, b1, wsc, bscp, t1, sc);
    mlp2_kernel<<<BB_, 256, 0, stream>>>(t1, sc, w2, b2, w3, b3, w4, b4, out);
}